// Round 19
// baseline (152.581 us; speedup 1.0000x reference)
//
#include <hip/hip_runtime.h>
#include <cstdint>
#include <cstddef>

typedef unsigned int u32;
typedef unsigned long long u64;

#define NB 8192
#define BIMG 2
#define WPR (NB / 64)   // 128 u64 words per mask row

// ---------------- workspace layout (bytes) ----------------
#define WS_KCOUNT 0
#define WS_KEYS   256                                // (unused, kept for layout)
#define WS_BOXES  (WS_KEYS + BIMG * NB * 8)          // (unused)
#define WS_PROB   (WS_BOXES + BIMG * NB * 16)        // (unused)
#define WS_SBOXES (WS_PROB + BIMG * NB * 4)          // 459008
#define WS_SPROB  (WS_SBOXES + BIMG * NB * 16)       // 721152
#define WS_REMV   (WS_SPROB + BIMG * NB * 4)         // (unused in fast path)
#define WS_MASK   (WS_REMV + BIMG * WPR * 8 + 256)   // 788992 (pad)
#define WS_ROWNZ  (WS_MASK + (size_t)BIMG * NB * WPR * 8)
#define WS_DIAG   (WS_ROWNZ + (size_t)BIMG * NB)         // 8-aligned
#define WS_DIAG2  (WS_DIAG + (size_t)BIMG * NB * 8)
#define WS_NEEDED (WS_DIAG2 + (size_t)BIMG * NB * 8)     // ~17.9 MB

__device__ inline u64 rdl64(u64 v, int lane) {
  u32 lo = (u32)__builtin_amdgcn_readlane((int)(u32)v, lane);
  u32 hi = (u32)__builtin_amdgcn_readlane((int)(u32)(v >> 32), lane);
  return ((u64)hi << 32) | lo;
}

__device__ inline u64 shflxor64(u64 v, int off) {
  u32 lo = (u32)v, hi = (u32)(v >> 32);
  lo = (u32)__shfl_xor((int)lo, off, 64);
  hi = (u32)__shfl_xor((int)hi, off, 64);
  return ((u64)hi << 32) | lo;
}

// key(label, n): byte-identical expression chain to the old decode kernel.
__device__ inline u64 make_key(float logit, int n) {
  float p = 1.0f / (1.0f + expf(-logit));
  bool valid = p > 0.5f;
  u32 e = valid ? (__float_as_uint(p) ^ 0x80000000u) : 0u;
  return ((u64)e << 32) | (u32)(~(u32)n);
}

// ---------------------------------------------------------------------------
// Kernel 2: FUSED decode + RANK-SORT. rank(i) = #{k : key[k] > key[i]}
// (keys unique -> rank == stable argsort-desc position). Comparison keys are
// computed inline from labels (4B load + sigmoid); the scattered element's
// box is decoded inline from its own offsets/anchors row. No decode kernel,
// no keys/boxes/prob intermediates. Positions >= K stay unwritten (provably
// unobservable: every consumer gates on < K). Block 0 writes kcount.
// Grid: (NB/64) x BIMG, 512 threads.
// ---------------------------------------------------------------------------
__global__ __launch_bounds__(512) void rank_kernel(const float* __restrict__ offsets,
                                                   const float* __restrict__ labels,
                                                   const float* __restrict__ anchors,
                                                   float4* __restrict__ sboxes,
                                                   float* __restrict__ sprob,
                                                   u32* __restrict__ kcount) {
  __shared__ u64 s_buf[8][64];     // wave-private key tiles (4 KB)
  __shared__ u32 s_cnt[64][9];     // padded: stride 9 -> conflict-free
  __shared__ u32 s_v[8];
  const int b = blockIdx.y;
  const int i0 = blockIdx.x * 64;
  const int w = threadIdx.x >> 6;
  const int lane = threadIdx.x & 63;
  const float* lb = labels + (size_t)b * NB;

  const float mylogit = lb[i0 + lane];
  const u64 myk = make_key(mylogit, i0 + lane);

  u32 cnt = 0, vcnt = 0;
  for (int t = 0; t < 16; ++t) {
    int n = w * 1024 + t * 64 + lane;
    s_buf[w][lane] = make_key(lb[n], n);             // wave-private: no barrier
    u32 c0 = 0, c1 = 0, c2 = 0, c3 = 0, v0 = 0;
#pragma unroll
    for (int jj = 0; jj < 64; jj += 4) {
      u64 k0 = s_buf[w][jj + 0];
      u64 k1 = s_buf[w][jj + 1];
      u64 k2 = s_buf[w][jj + 2];
      u64 k3 = s_buf[w][jj + 3];
      c0 += (k0 > myk) ? 1u : 0u;
      c1 += (k1 > myk) ? 1u : 0u;
      c2 += (k2 > myk) ? 1u : 0u;
      c3 += (k3 > myk) ? 1u : 0u;
      v0 += (((u32)(k0 >> 32)) != 0u) ? 1u : 0u;
      v0 += (((u32)(k1 >> 32)) != 0u) ? 1u : 0u;
      v0 += (((u32)(k2 >> 32)) != 0u) ? 1u : 0u;
      v0 += (((u32)(k3 >> 32)) != 0u) ? 1u : 0u;
    }
    cnt += c0 + c1 + c2 + c3;
    vcnt += v0;
  }
  s_cnt[lane][w] = cnt;
  if (lane == 0) s_v[w] = vcnt;
  __syncthreads();

  if (threadIdx.x < 64) {
    int n = i0 + threadIdx.x;           // == i0 + lane for wave 0
    u32 rank = 0;
#pragma unroll
    for (int q = 0; q < 8; ++q) rank += s_cnt[threadIdx.x][q];
    bool valid = ((u32)(myk >> 32)) != 0u;
    if (valid) {
      // inline box decode (byte-identical expressions to the old decode)
      float p = 1.0f / (1.0f + expf(-mylogit));
      const float4 an = ((const float4*)anchors)[n];   // x1,y1,x2,y2
      float acx = (an.x + an.z) / 2.0f;
      float acy = (an.y + an.w) / 2.0f;
      float aw = an.z - an.x;
      float ah = an.w - an.y;
      const float4 of = ((const float4*)offsets)[(size_t)b * NB + n];
      float cx = of.x * aw / 10.0f + acx;
      float cy = of.y * ah / 10.0f + acy;
      float wd = expf(of.z / 5.0f) * aw;
      float ht = expf(of.w / 5.0f) * ah;
      float4 bx;
      bx.x = cx - wd / 2.0f;
      bx.y = cy - ht / 2.0f;
      bx.z = cx + wd / 2.0f;
      bx.w = cy + ht / 2.0f;
      sboxes[(size_t)b * NB + rank] = bx;
      sprob[(size_t)b * NB + rank]  = p;
    }
  }
  if (blockIdx.x == 0 && threadIdx.x == 0) {
    u32 K = 0;
#pragma unroll
    for (int q = 0; q < 8; ++q) K += s_v[q];
    kcount[b] = K;
  }
}

// ---------------------------------------------------------------------------
// Kernel 4: overlap bitmask build — 8-ROW TILES with bj reuse (r18, verified).
// ---------------------------------------------------------------------------
#define MROWS 8

__global__ __launch_bounds__(256) void mask_kernel(const float4* __restrict__ sboxes,
                                                   const u32* __restrict__ kcount,
                                                   u64* __restrict__ mask,
                                                   unsigned char* __restrict__ rownz,
                                                   u64* __restrict__ diag,
                                                   u64* __restrict__ diag2) {
  const int b = blockIdx.y;
  const int K = (int)kcount[b];
  const int i0 = blockIdx.x * MROWS;
  if (i0 >= K) return;
  const int wv = threadIdx.x >> 6;     // wave 0..3
  const int lane = threadIdx.x & 63;
  const int tc = i0 >> 6;              // same chunk for all 8 rows
  const int NC = min(WPR, (K + 63) >> 6);
  __shared__ float4 s_bi[MROWS];
  __shared__ float s_ai[MROWS];
  __shared__ u32 s_anyw[4];
  if (threadIdx.x < MROWS) {
    float4 v = sboxes[(size_t)b * NB + i0 + threadIdx.x];
    s_bi[threadIdx.x] = v;
    s_ai[threadIdx.x] = (v.z - v.x) * (v.w - v.y);
  }
  __syncthreads();

  const float4* sb = sboxes + (size_t)b * NB;
  u64* mbase = mask + (size_t)b * NB * WPR;
  u32 anyr = 0;                        // bit r: row i0+r has a nonzero word

  for (int w = tc + wv; w < NC; w += 4) {
    const int j = w * 64 + lane;
    const float4 bj = sb[j];
    const float area_j = (bj.z - bj.x) * (bj.w - bj.y);
    u64 words[MROWS];
#pragma unroll
    for (int r = 0; r < MROWS; ++r) {
      float4 bi = s_bi[r];
      float lx = fmaxf(bi.x, bj.x);
      float ly = fmaxf(bi.y, bj.y);
      float rx = fminf(bi.z, bj.z);
      float ry = fminf(bi.w, bj.w);
      float iw = fmaxf(rx - lx, 0.0f);
      float ih = fmaxf(ry - ly, 0.0f);
      float inter = iw * ih;
      float iou = inter / (s_ai[r] + area_j - inter);
      bool pred = (j > i0 + r) && (j < K) && (iou > 0.5f);
      words[r] = __ballot(pred);
    }
#pragma unroll
    for (int r = 0; r < MROWS; ++r) anyr |= (words[r] != 0ull) ? (1u << r) : 0u;
    if (lane == 0) {
#pragma unroll
      for (int r = 0; r < MROWS; ++r) {
        int i = i0 + r;
        if (i < K) {
          mbase[(size_t)i * WPR + w] = words[r];
          if (w == tc)          diag[(size_t)b * NB + i]  = words[r];
          else if (w == tc + 1) diag2[(size_t)b * NB + i] = words[r];
        }
      }
    }
  }
  if (lane == 0) s_anyw[wv] = anyr;
  __syncthreads();
  if (threadIdx.x < MROWS) {
    int i = i0 + threadIdx.x;
    if (i < K) {
      u32 a = (s_anyw[0] | s_anyw[1] | s_anyw[2] | s_anyw[3]) >> threadIdx.x;
      rownz[(size_t)b * NB + i] = (unsigned char)(a & 1u);
    }
  }
}

// ---------------------------------------------------------------------------
// Kernel 5: PAIRED chunked greedy scan + fused output (r16, verified 92us).
// ---------------------------------------------------------------------------
#define SCAN_WAVES 8
#define MAXROWS 10

__device__ inline void resolve_diag(u64& rc, u64 dw) {
  u64 nzd = __ballot(dw != 0ull) & ~rc;
  while (nzd) {
    int tt = __builtin_ctzll(nzd);
    rc |= rdl64(dw, tt);
    nzd &= ~(1ull << tt) & ~rc;
  }
}

__global__ __launch_bounds__(512) void scan_kernel(const u64* __restrict__ mask,
                                                   const u64* __restrict__ diag,
                                                   const u64* __restrict__ diag2,
                                                   const unsigned char* __restrict__ rownz,
                                                   const u32* __restrict__ kcount,
                                                   const float4* __restrict__ sboxes,
                                                   const float* __restrict__ sprob,
                                                   float* __restrict__ out) {
  __shared__ u64 s_remv[WPR];               // finalized rc words (1 KB)
  __shared__ u64 s_slotE[2][SCAN_WAVES];    // posts of word 2t+2
  __shared__ u64 s_slotO[2][SCAN_WAVES];    // posts of word 2t+3
  __shared__ u64 s_kuA, s_kuB, s_nzwA, s_nzwB;
  const int b = blockIdx.x;
  const int tid = threadIdx.x;
  const int w = tid >> 6;                   // wave id 0..7
  const int l = tid & 63;
  const int K = (int)kcount[b];
  const u64* mb = mask + (size_t)b * NB * WPR;
  const u64* dg = diag + (size_t)b * NB;
  const u64* dg2 = diag2 + (size_t)b * NB;
  const unsigned char* nzb = rownz + (size_t)b * NB;
  const int NC = min(WPR, (K + 63) >> 6);
  const int NCL = min(NC, 64);
  const int NP = (NC + 1) >> 1;             // chunk pairs

  if (tid < 2 * SCAN_WAVES) { ((u64*)s_slotE)[tid] = 0; ((u64*)s_slotO)[tid] = 0; }

  u64 plo = 0, phi = 0;
  const bool okLo = (l < NCL);
  const bool okHi = (64 + l) < NC;
  u64 LA[MAXROWS], HA[MAXROWS], LB[MAXROWS], HB[MAXROWS];
  u64 bqA[MAXROWS], bqB[MAXROWS];
  u64 dwA = 0, dwB = 0, cw = 0;
  unsigned char nzcA = 0, nzcB = 0;

  if (w == 0 && NP > 0) {
    int rA = l, rB = 64 + l;
    dwA = (rA < K) ? dg[rA] : 0ull;
    dwB = (rB < K) ? dg[rB] : 0ull;
    cw  = (rA < K) ? dg2[rA] : 0ull;
    nzcA = (rA < K) ? nzb[rA] : (unsigned char)0;
    nzcB = (rB < K) ? nzb[rB] : (unsigned char)0;
    u64 a0 = __ballot(nzcA != 0), b0 = __ballot(nzcB != 0);
    if (l == 0) { s_nzwA = a0; s_nzwB = b0; }
  }
  __syncthreads();

  for (int t = 0; t < NP; ++t) {
    const int cA = 2 * t, cB = 2 * t + 1;
    const bool hasB = (cB < NC);
    // ---------------- phase 1 ----------------
    if (w == 0) {
      u64 dwA_n = 0, dwB_n = 0, cw_n = 0;
      unsigned char nzA_n = 0, nzB_n = 0;
      if (t + 1 < NP) {
        int rA = (t + 1) * 128 + l, rB = (t + 1) * 128 + 64 + l;
        dwA_n = (rA < K) ? dg[rA] : 0ull;
        dwB_n = (rB < K) ? dg[rB] : 0ull;
        cw_n  = (rA < K) ? dg2[rA] : 0ull;
        nzA_n = (rA < K) ? nzb[rA] : (unsigned char)0;
        nzB_n = (rB < K) ? nzb[rB] : (unsigned char)0;
      }
      int pr = (t + 1) & 1;
      u64 valA = s_slotE[pr][l & (SCAN_WAVES - 1)];
      u64 valB = s_slotO[pr][l & (SCAN_WAVES - 1)];
#pragma unroll
      for (int off = 1; off < SCAN_WAVES; off <<= 1) {
        valA |= shflxor64(valA, off);
        valB |= shflxor64(valB, off);
      }
      int loA = cA * 64;
      u64 tailA = (loA + 64 <= K) ? 0ull : ((~0ull) << (K - loA));
      u64 rcA = valA | tailA;
      u64 nzwA = __ballot(nzcA != 0);
      resolve_diag(rcA, dwA);
      u64 kuA = (~rcA) & nzwA;
      u64 m = ((~rcA >> l) & 1ull) ? cw : 0ull;
#pragma unroll
      for (int off = 32; off > 0; off >>= 1) m |= shflxor64(m, off);
      u64 rcB = ~0ull, kuB = 0;
      if (hasB) {
        int loB = cB * 64;
        u64 tailB = (loB + 64 <= K) ? 0ull : ((~0ull) << (K - loB));
        rcB = valB | tailB | m;
        u64 nzwB = __ballot(nzcB != 0);
        resolve_diag(rcB, dwB);
        kuB = (~rcB) & nzwB;
      }
      if (l == 0) {
        s_remv[cA] = rcA;
        if (hasB) s_remv[cB] = rcB;
        s_kuA = kuA; s_kuB = kuB;
      }
      dwA = dwA_n; dwB = dwB_n; cw = cw_n; nzcA = nzA_n; nzcB = nzB_n;
    } else {
      u64 kkA = (s_nzwA >> ((w - 1) * MAXROWS)) & ((1ull << MAXROWS) - 1ull);
      u64 kkB = (s_nzwB >> ((w - 1) * MAXROWS)) & ((1ull << MAXROWS) - 1ull);
#pragma unroll
      for (int q = 0; q < MAXROWS; ++q) {
        bool hA = (kkA != 0ull);
        int tA = hA ? __builtin_ctzll(kkA) : 0;
        if (hA) kkA &= kkA - 1;
        bqA[q] = hA ? (1ull << ((w - 1) * MAXROWS + tA)) : 0ull;
        LA[q] = 0; HA[q] = 0;
        if (hA) {
          const u64* rp = mb + (size_t)(cA * 64 + (w - 1) * MAXROWS + tA) * WPR;
          if (okLo) LA[q] = rp[l];
          if (okHi) HA[q] = rp[64 + l];
        }
        bool hB = (kkB != 0ull);
        int tB = hB ? __builtin_ctzll(kkB) : 0;
        if (hB) kkB &= kkB - 1;
        bqB[q] = hB ? (1ull << ((w - 1) * MAXROWS + tB)) : 0ull;
        LB[q] = 0; HB[q] = 0;
        if (hB) {
          const u64* rp = mb + (size_t)(cB * 64 + (w - 1) * MAXROWS + tB) * WPR;
          if (okLo) LB[q] = rp[l];
          if (okHi) HB[q] = rp[64 + l];
        }
      }
    }
    __syncthreads();                     // barrier A

    // ---------------- phase 2 (register/LDS only) ----------------
    if (w == 0) {
      u64 a1 = __ballot(nzcA != 0), b1 = __ballot(nzcB != 0);
      if (l == 0) { s_nzwA = a1; s_nzwB = b1; }
    } else {
      u64 kuA = s_kuA, kuB = s_kuB;
#pragma unroll
      for (int q = 0; q < MAXROWS; ++q) {
        if (kuA & bqA[q]) { plo |= LA[q]; phi |= HA[q]; }
        if (kuB & bqB[q]) { plo |= LB[q]; phi |= HB[q]; }
      }
      int wE = cA + 2, wO = cA + 3;
      u64 vE = (wE < 64) ? plo : phi;
      if (l == (wE & 63)) s_slotE[t & 1][w] = vE;
      u64 vO = (wO < 64) ? plo : phi;
      if (l == (wO & 63)) s_slotO[t & 1][w] = vO;
    }
    __syncthreads();                     // barrier B
  }

  // ---------------- fused output ----------------
  const float4* sbx = sboxes + (size_t)b * NB;
  const float* spb = sprob + (size_t)b * NB;
  for (int p = tid; p < NB; p += 512) {
    bool kp = false;
    if (p < K) {
      u64 wv = s_remv[p >> 6];
      kp = !((wv >> (p & 63)) & 1ull);
    }
    float4 bv = sbx[p];
    if (!kp) { bv.x = 0.0f; bv.y = 0.0f; bv.z = 0.0f; bv.w = 0.0f; }
    ((float4*)out)[(size_t)b * NB + p] = bv;
    out[(size_t)BIMG * NB * 4 + (size_t)b * NB + p] = kp ? spb[p] : 0.0f;
    out[(size_t)BIMG * NB * 5 + (size_t)b * NB + p] = kp ? 1.0f : 0.0f;
  }
}

// ---------------------------------------------------------------------------
// Fallback NMS kernel (used only if workspace is too small)
// ---------------------------------------------------------------------------
__global__ __launch_bounds__(1024) void nms_kernel(const float4* __restrict__ sboxes,
                                                   const float* __restrict__ sprob,
                                                   const u32* __restrict__ kcount,
                                                   float* __restrict__ out) {
  __shared__ float4 sb[NB];
  __shared__ unsigned char flag[NB];
  const int b = blockIdx.x;
  const int t = threadIdx.x;
  const int K = (int)kcount[b];

  for (int p = t; p < NB; p += 1024) {
    sb[p] = sboxes[(size_t)b * NB + p];
    flag[p] = (p < K) ? (unsigned char)0 : (unsigned char)1;
  }
  __syncthreads();

  for (int i = 0; i < K; ++i) {
    if (flag[i]) continue;
    float4 bi = sb[i];
    float area_i = (bi.z - bi.x) * (bi.w - bi.y);
    for (int j = i + 1 + t; j < K; j += 1024) {
      float4 bj = sb[j];
      float lx = fmaxf(bi.x, bj.x);
      float ly = fmaxf(bi.y, bj.y);
      float rx = fminf(bi.z, bj.z);
      float ry = fminf(bi.w, bj.w);
      float iw = fmaxf(rx - lx, 0.0f);
      float ih = fmaxf(ry - ly, 0.0f);
      float inter = iw * ih;
      float area_j = (bj.z - bj.x) * (bj.w - bj.y);
      float iou = inter / (area_i + area_j - inter);
      if (iou > 0.5f) flag[j] = (unsigned char)1;
    }
    __syncthreads();
  }

  float4* oboxes = (float4*)(out) + (size_t)b * NB;
  float* oscores = out + (size_t)BIMG * NB * 4 + (size_t)b * NB;
  float* okeep   = out + (size_t)BIMG * NB * 5 + (size_t)b * NB;
  for (int p = t; p < NB; p += 1024) {
    bool kp = (p < K) && (flag[p] == 0);
    float4 bv = sb[p];
    if (!kp) { bv.x = 0.0f; bv.y = 0.0f; bv.z = 0.0f; bv.w = 0.0f; }
    oboxes[p] = bv;
    oscores[p] = kp ? sprob[(size_t)b * NB + p] : 0.0f;
    okeep[p] = kp ? 1.0f : 0.0f;
  }
}

// ---------------------------------------------------------------------------
extern "C" void kernel_launch(void* const* d_in, const int* in_sizes, int n_in,
                              void* d_out, int out_size, void* d_ws, size_t ws_size,
                              hipStream_t stream) {
  const float* offsets = (const float*)d_in[0];   // [B,N,4] f32
  const float* labels  = (const float*)d_in[1];   // [B,N,1] f32
  const float* anchors = (const float*)d_in[2];   // [N,4]   f32
  float* out = (float*)d_out;

  char* ws = (char*)d_ws;
  u32*    kcount = (u32*)(ws + WS_KCOUNT);
  float4* sboxes = (float4*)(ws + WS_SBOXES);
  float*  sprob  = (float*)(ws + WS_SPROB);

  rank_kernel<<<dim3(NB / 64, BIMG), 512, 0, stream>>>(
      offsets, labels, anchors, sboxes, sprob, kcount);

  if (ws_size >= WS_NEEDED) {
    u64*    mask   = (u64*)(ws + WS_MASK);
    unsigned char* rownz = (unsigned char*)(ws + WS_ROWNZ);
    u64*    diag   = (u64*)(ws + WS_DIAG);
    u64*    diag2  = (u64*)(ws + WS_DIAG2);

    mask_kernel<<<dim3(NB / MROWS, BIMG), 256, 0, stream>>>(
        sboxes, kcount, mask, rownz, diag, diag2);

    scan_kernel<<<BIMG, 512, 0, stream>>>(mask, diag, diag2, rownz, kcount,
                                          sboxes, sprob, out);
  } else {
    nms_kernel<<<BIMG, 1024, 0, stream>>>(sboxes, sprob, kcount, out);
  }
}